// Round 1
// baseline (605.471 us; speedup 1.0000x reference)
//
#include <hip/hip_runtime.h>

// B=4, S=2048, D=512, H=8, DK=DV=64
typedef __attribute__((ext_vector_type(8))) short short8;
typedef __attribute__((ext_vector_type(4))) float f32x4;

__device__ __forceinline__ short f2bf(float f) {
  union { float f; unsigned u; } x; x.f = f;
  return (short)((x.u + 0x7FFFu + ((x.u >> 16) & 1u)) >> 16);
}

// Wt[m][n][k] = W_m[k][n], bf16  (3 x 512 x 512)
__global__ __launch_bounds__(256) void prep_wt_k(const float* __restrict__ Wq,
    const float* __restrict__ Wk, const float* __restrict__ Wv,
    short* __restrict__ wt) {
  int idx = blockIdx.x * 256 + threadIdx.x;       // 0 .. 3*512*512-1
  int m = idx >> 18;
  int r = idx & 0x3FFFF;
  int k = r >> 9, n = r & 511;
  const float* W = (m == 0) ? Wq : (m == 1) ? Wk : Wv;
  wt[(m << 18) + (n << 9) + k] = f2bf(W[(k << 9) + n]);
}

// X[8192][512] f32 @ Wt[n][k] bf16 -> qh/kh [b][h][s][64] bf16, vt [b][h][dv][s] bf16
__global__ __launch_bounds__(64) void proj_k(const float* __restrict__ q,
    const float* __restrict__ k_, const float* __restrict__ v,
    const short* __restrict__ wt, short* __restrict__ qh,
    short* __restrict__ kh, short* __restrict__ vt) {
  int bid = blockIdx.x;
  int mat = bid >> 10;                 // 0=Q 1=K 2=V
  int t = bid & 1023;
  int tm = t >> 3, tn = t & 7;         // 128 x 8 tiles of 64x64
  const float* X = (mat == 0) ? q : (mat == 1) ? k_ : v;
  const short* W = wt + ((size_t)mat << 18);
  int lane = threadIdx.x;
  int lr = lane & 15, lg = lane >> 4;
  int m0 = tm << 6, n0 = tn << 6;
  f32x4 acc[4][4];
  #pragma unroll
  for (int i = 0; i < 4; i++)
    #pragma unroll
    for (int j = 0; j < 4; j++) acc[i][j] = (f32x4){0.f, 0.f, 0.f, 0.f};
  for (int k0 = 0; k0 < 512; k0 += 32) {
    short8 a[4], bfr[4];
    #pragma unroll
    for (int i = 0; i < 4; i++) {
      const float* p = X + (size_t)(m0 + 16 * i + lr) * 512 + k0 + 8 * lg;
      float4 f0 = *(const float4*)p;
      float4 f1 = *(const float4*)(p + 4);
      short8 tt;
      tt[0] = f2bf(f0.x); tt[1] = f2bf(f0.y); tt[2] = f2bf(f0.z); tt[3] = f2bf(f0.w);
      tt[4] = f2bf(f1.x); tt[5] = f2bf(f1.y); tt[6] = f2bf(f1.z); tt[7] = f2bf(f1.w);
      a[i] = tt;
    }
    #pragma unroll
    for (int j = 0; j < 4; j++)
      bfr[j] = *(const short8*)(W + (size_t)(n0 + 16 * j + lr) * 512 + k0 + 8 * lg);
    #pragma unroll
    for (int i = 0; i < 4; i++)
      #pragma unroll
      for (int j = 0; j < 4; j++)
        acc[i][j] = __builtin_amdgcn_mfma_f32_16x16x32_bf16(a[i], bfr[j], acc[i][j], 0, 0, 0);
  }
  #pragma unroll
  for (int i = 0; i < 4; i++)
    #pragma unroll
    for (int j = 0; j < 4; j++)
      #pragma unroll
      for (int r = 0; r < 4; r++) {
        int row = m0 + 16 * i + lg * 4 + r;   // token index
        int col = n0 + 16 * j + lr;           // h*64 + d
        int bb = row >> 11, s = row & 2047;
        int h = col >> 6, d = col & 63;
        short val = f2bf(acc[i][j][r]);
        if (mat == 0)      qh[((size_t)((bb * 8 + h) * 2048 + s) << 6) + d] = val;
        else if (mat == 1) kh[((size_t)((bb * 8 + h) * 2048 + s) << 6) + d] = val;
        else               vt[((size_t)((bb * 8 + h) * 64 + d) << 11) + s] = val;
      }
}

__global__ __launch_bounds__(256) void attn_k(const short* __restrict__ qh,
    const short* __restrict__ kh, const short* __restrict__ vt,
    const float* __restrict__ mask, const float* __restrict__ gamma_p,
    float* __restrict__ out, float* __restrict__ attn_out) {
  __shared__ __align__(16) short P_lds[4][16][40];  // +8 pad: 2-way banks (free)
  int bid = blockIdx.x;
  int bh = bid >> 5;            // b*8+h
  int qblk = bid & 31;
  int bb = bh >> 3;
  int wave = threadIdx.x >> 6;
  int lane = threadIdx.x & 63;
  int lr = lane & 15, lg = lane >> 4;
  int qb = qblk * 64 + wave * 16;           // this wave's 16 q rows
  const short* Kb = kh + (size_t)bh * (2048 * 64);
  const short* Qb = qh + (size_t)bh * (2048 * 64);
  const short* Vb = vt + (size_t)bh * (64 * 2048);
  const float* Mb = mask + (size_t)bb * (2048 * 2048);
  float gamma = gamma_p[0];
  float shift = fmaxf(gamma, 0.f) + 16.0f;  // safe fixed shift: scores <= gamma + ~6

  short8 qf0 = *(const short8*)(Qb + (size_t)(qb + lr) * 64 + 8 * lg);
  short8 qf1 = *(const short8*)(Qb + (size_t)(qb + lr) * 64 + 32 + 8 * lg);

  // ---- pass A: row sums of exp(s - shift) ----
  float lsum[4] = {0.f, 0.f, 0.f, 0.f};
  for (int kc = 0; kc < 2048; kc += 16) {
    short8 kf0 = *(const short8*)(Kb + (size_t)(kc + lr) * 64 + 8 * lg);
    short8 kf1 = *(const short8*)(Kb + (size_t)(kc + lr) * 64 + 32 + 8 * lg);
    f32x4 s = (f32x4){0.f, 0.f, 0.f, 0.f};
    s = __builtin_amdgcn_mfma_f32_16x16x32_bf16(qf0, kf0, s, 0, 0, 0);
    s = __builtin_amdgcn_mfma_f32_16x16x32_bf16(qf1, kf1, s, 0, 0, 0);
    #pragma unroll
    for (int r = 0; r < 4; r++) {
      int qg = qb + lg * 4 + r;
      float sc = s[r] * 0.125f + gamma * Mb[(size_t)qg * 2048 + kc + lr];
      lsum[r] += __expf(sc - shift);
    }
  }
  #pragma unroll
  for (int r = 0; r < 4; r++) {
    float vs = lsum[r];
    vs += __shfl_xor(vs, 1);
    vs += __shfl_xor(vs, 2);
    vs += __shfl_xor(vs, 4);
    vs += __shfl_xor(vs, 8);
    lsum[r] = 1.0f / vs;     // inv row sum, uniform across 16-lane group
  }

  // ---- pass B: recompute scores, write attn, PV ----
  f32x4 oacc[4];
  #pragma unroll
  for (int j = 0; j < 4; j++) oacc[j] = (f32x4){0.f, 0.f, 0.f, 0.f};

  for (int kc = 0; kc < 2048; kc += 32) {
    #pragma unroll
    for (int t2 = 0; t2 < 2; t2++) {
      int c0 = kc + 16 * t2;
      short8 kf0 = *(const short8*)(Kb + (size_t)(c0 + lr) * 64 + 8 * lg);
      short8 kf1 = *(const short8*)(Kb + (size_t)(c0 + lr) * 64 + 32 + 8 * lg);
      f32x4 s = (f32x4){0.f, 0.f, 0.f, 0.f};
      s = __builtin_amdgcn_mfma_f32_16x16x32_bf16(qf0, kf0, s, 0, 0, 0);
      s = __builtin_amdgcn_mfma_f32_16x16x32_bf16(qf1, kf1, s, 0, 0, 0);
      #pragma unroll
      for (int r = 0; r < 4; r++) {
        int qg = qb + lg * 4 + r;
        float sc = s[r] * 0.125f + gamma * Mb[(size_t)qg * 2048 + c0 + lr];
        float p = __expf(sc - shift) * lsum[r];
        attn_out[((size_t)bh * 2048 + qg) * 2048 + c0 + lr] = p;
        P_lds[wave][lg * 4 + r][16 * t2 + lr] = f2bf(p);
      }
    }
    asm volatile("s_waitcnt lgkmcnt(0)" ::: "memory");  // P writes -> reads (wave-local)
    short8 pf = *(const short8*)(&P_lds[wave][lr][8 * lg]);
    #pragma unroll
    for (int j = 0; j < 4; j++) {
      short8 vf = *(const short8*)(Vb + (size_t)(16 * j + lr) * 2048 + kc + 8 * lg);
      oacc[j] = __builtin_amdgcn_mfma_f32_16x16x32_bf16(pf, vf, oacc[j], 0, 0, 0);
    }
    asm volatile("s_waitcnt lgkmcnt(0)" ::: "memory");
  }

  int h = bh & 7;
  #pragma unroll
  for (int j = 0; j < 4; j++)
    #pragma unroll
    for (int r = 0; r < 4; r++) {
      int qg = qb + lg * 4 + r;
      out[(size_t)(bb * 2048 + qg) * 512 + h * 64 + 16 * j + lr] = oacc[j][r];
    }
}

extern "C" void kernel_launch(void* const* d_in, const int* in_sizes, int n_in,
                              void* d_out, int out_size, void* d_ws, size_t ws_size,
                              hipStream_t stream) {
  const float* q    = (const float*)d_in[0];
  const float* k    = (const float*)d_in[1];
  const float* v    = (const float*)d_in[2];
  const float* mask = (const float*)d_in[3];
  const float* Wq   = (const float*)d_in[4];
  const float* Wk   = (const float*)d_in[5];
  const float* Wv   = (const float*)d_in[6];
  const float* gma  = (const float*)d_in[7];
  float* out = (float*)d_out;
  float* attn_out = out + (size_t)4 * 2048 * 512;       // out first, then attn

  short* wt = (short*)d_ws;                              // 1.5 MB
  short* qh = (short*)((char*)d_ws + (2u << 20));        // 8 MB
  short* kh = qh + (size_t)4 * 8 * 2048 * 64;            // 8 MB
  short* vt = kh + (size_t)4 * 8 * 2048 * 64;            // 8 MB (transposed V)

  hipLaunchKernelGGL(prep_wt_k, dim3(3072), dim3(256), 0, stream, Wq, Wk, Wv, wt);
  hipLaunchKernelGGL(proj_k,    dim3(3072), dim3(64),  0, stream, q, k, v, wt, qh, kh, vt);
  hipLaunchKernelGGL(attn_k,    dim3(1024), dim3(256), 0, stream, qh, kh, vt, mask, gma,
                     out, attn_out);
}

// Round 2
// 586.874 us; speedup vs baseline: 1.0317x; 1.0317x over previous
//
#include <hip/hip_runtime.h>

// B=4, S=2048, D=512, H=8, DK=DV=64
typedef __attribute__((ext_vector_type(8))) short short8;
typedef __attribute__((ext_vector_type(4))) float f32x4;

__device__ __forceinline__ short f2bf(float f) {
  union { float f; unsigned u; } x; x.f = f;
  return (short)((x.u + 0x7FFFu + ((x.u >> 16) & 1u)) >> 16);
}

// Wt[m][n][k] = W_m[k][n], bf16  (3 x 512 x 512)
__global__ __launch_bounds__(256) void prep_wt_k(const float* __restrict__ Wq,
    const float* __restrict__ Wk, const float* __restrict__ Wv,
    short* __restrict__ wt) {
  int idx = blockIdx.x * 256 + threadIdx.x;
  int m = idx >> 18;
  int r = idx & 0x3FFFF;
  int k = r >> 9, n = r & 511;
  const float* W = (m == 0) ? Wq : (m == 1) ? Wk : Wv;
  wt[(m << 18) + (n << 9) + k] = f2bf(W[(k << 9) + n]);
}

// convert q,k,v f32 -> bf16 [3][8192][512]
__global__ __launch_bounds__(256) void xcvt_k(const float* __restrict__ q,
    const float* __restrict__ k_, const float* __restrict__ v,
    short* __restrict__ xb) {
  int i = blockIdx.x * 256 + threadIdx.x;      // 8-elem units, 3*524288 total
  int m = i >> 19;                             // 524288 units per matrix
  int r = i & 0x7FFFF;
  const float* X = (m == 0) ? q : (m == 1) ? k_ : v;
  float4 f0 = ((const float4*)X)[2 * r];
  float4 f1 = ((const float4*)X)[2 * r + 1];
  short8 t;
  t[0] = f2bf(f0.x); t[1] = f2bf(f0.y); t[2] = f2bf(f0.z); t[3] = f2bf(f0.w);
  t[4] = f2bf(f1.x); t[5] = f2bf(f1.y); t[6] = f2bf(f1.z); t[7] = f2bf(f1.w);
  *(short8*)(xb + (size_t)i * 8) = t;
}

// X[8192][512] @ Wt[n][k] -> qh/kh [b][h][s][64] bf16, vt [b][h][dv][s] bf16
template<int BF>
__global__ __launch_bounds__(64) void proj_k(const float* __restrict__ q,
    const float* __restrict__ k_, const float* __restrict__ v,
    const short* __restrict__ xb, const short* __restrict__ wt,
    short* __restrict__ qh, short* __restrict__ kh, short* __restrict__ vt) {
  int bid = blockIdx.x;
  int mat = bid >> 10;
  int t = bid & 1023;
  int tm = t >> 3, tn = t & 7;
  const float* X = (mat == 0) ? q : (mat == 1) ? k_ : v;
  const short* Xb = xb + ((size_t)mat << 22);
  const short* W = wt + ((size_t)mat << 18);
  int lane = threadIdx.x;
  int lr = lane & 15, lg = lane >> 4;
  int m0 = tm << 6, n0 = tn << 6;
  f32x4 acc[4][4];
  #pragma unroll
  for (int i = 0; i < 4; i++)
    #pragma unroll
    for (int j = 0; j < 4; j++) acc[i][j] = (f32x4){0.f, 0.f, 0.f, 0.f};
  for (int k0 = 0; k0 < 512; k0 += 32) {
    short8 a[4], bfr[4];
    #pragma unroll
    for (int i = 0; i < 4; i++) {
      if (BF) {
        a[i] = *(const short8*)(Xb + (size_t)(m0 + 16 * i + lr) * 512 + k0 + 8 * lg);
      } else {
        const float* p = X + (size_t)(m0 + 16 * i + lr) * 512 + k0 + 8 * lg;
        float4 f0 = *(const float4*)p;
        float4 f1 = *(const float4*)(p + 4);
        short8 tt;
        tt[0] = f2bf(f0.x); tt[1] = f2bf(f0.y); tt[2] = f2bf(f0.z); tt[3] = f2bf(f0.w);
        tt[4] = f2bf(f1.x); tt[5] = f2bf(f1.y); tt[6] = f2bf(f1.z); tt[7] = f2bf(f1.w);
        a[i] = tt;
      }
    }
    #pragma unroll
    for (int j = 0; j < 4; j++)
      bfr[j] = *(const short8*)(W + (size_t)(n0 + 16 * j + lr) * 512 + k0 + 8 * lg);
    #pragma unroll
    for (int i = 0; i < 4; i++)
      #pragma unroll
      for (int j = 0; j < 4; j++)
        acc[i][j] = __builtin_amdgcn_mfma_f32_16x16x32_bf16(a[i], bfr[j], acc[i][j], 0, 0, 0);
  }
  #pragma unroll
  for (int i = 0; i < 4; i++)
    #pragma unroll
    for (int j = 0; j < 4; j++)
      #pragma unroll
      for (int r = 0; r < 4; r++) {
        int row = m0 + 16 * i + lg * 4 + r;
        int col = n0 + 16 * j + lr;
        int bb = row >> 11, s = row & 2047;
        int h = col >> 6, d = col & 63;
        short val = f2bf(acc[i][j][r]);
        if (mat == 0)      qh[((size_t)((bb * 8 + h) * 2048 + s) << 6) + d] = val;
        else if (mat == 1) kh[((size_t)((bb * 8 + h) * 2048 + s) << 6) + d] = val;
        else               vt[((size_t)((bb * 8 + h) * 64 + d) << 11) + s] = val;
      }
}

// swapped-operand attention: per-lane owns 4 contiguous k columns of one q row
__global__ __launch_bounds__(128) void attn_k(const short* __restrict__ qh,
    const short* __restrict__ kh, const short* __restrict__ vt,
    const float* __restrict__ mask, const float* __restrict__ gamma_p,
    float* __restrict__ out, float* __restrict__ attn_out) {
  __shared__ __align__(16) short P_lds[2][16][40];   // +8 pad
  int bid = blockIdx.x;
  int bh = bid >> 6;             // b*8+h
  int qblk = bid & 63;           // 32 q rows per block
  int bb = bh >> 3, h = bh & 7;
  int wave = threadIdx.x >> 6;
  int lane = threadIdx.x & 63;
  int lr = lane & 15, lg = lane >> 4;
  int qb = (qblk << 5) + (wave << 4);
  int qg = qb + lr;                                  // this lane's q row
  const short* Kb = kh + (size_t)bh * (2048 * 64);
  const short* Qb = qh + (size_t)bh * (2048 * 64);
  const short* Vb = vt + (size_t)bh * (64 * 2048);
  const float* Mrow = mask + (size_t)bb * (2048 * 2048) + (size_t)qg * 2048;
  float* Arow = attn_out + ((size_t)bh * 2048 + qg) * 2048;
  float gamma = gamma_p[0];
  float shift = fmaxf(gamma, 0.f) + 16.0f;

  short8 qf0 = *(const short8*)(Qb + (size_t)qg * 64 + 8 * lg);
  short8 qf1 = *(const short8*)(Qb + (size_t)qg * 64 + 32 + 8 * lg);

  // ---- pass A: row sums ----
  float lsum = 0.f;
  for (int kc = 0; kc < 2048; kc += 32) {
    #pragma unroll
    for (int t2 = 0; t2 < 2; ++t2) {
      int c0 = kc + (t2 << 4);
      short8 kf0 = *(const short8*)(Kb + (size_t)(c0 + lr) * 64 + 8 * lg);
      short8 kf1 = *(const short8*)(Kb + (size_t)(c0 + lr) * 64 + 32 + 8 * lg);
      f32x4 s = (f32x4){0.f, 0.f, 0.f, 0.f};
      s = __builtin_amdgcn_mfma_f32_16x16x32_bf16(kf0, qf0, s, 0, 0, 0);
      s = __builtin_amdgcn_mfma_f32_16x16x32_bf16(kf1, qf1, s, 0, 0, 0);
      float4 m4 = *(const float4*)(Mrow + c0 + (lg << 2));
      lsum += __expf(fmaf(s[0], 0.125f, fmaf(m4.x, gamma, -shift)));
      lsum += __expf(fmaf(s[1], 0.125f, fmaf(m4.y, gamma, -shift)));
      lsum += __expf(fmaf(s[2], 0.125f, fmaf(m4.z, gamma, -shift)));
      lsum += __expf(fmaf(s[3], 0.125f, fmaf(m4.w, gamma, -shift)));
    }
  }
  lsum += __shfl_xor(lsum, 16);
  lsum += __shfl_xor(lsum, 32);
  float inv = 1.0f / lsum;      // uniform per lane: 1/rowsum for q=qg

  // ---- pass B: recompute, write attn (float4), PV ----
  f32x4 oacc[4];
  #pragma unroll
  for (int j = 0; j < 4; j++) oacc[j] = (f32x4){0.f, 0.f, 0.f, 0.f};

  for (int kc = 0; kc < 2048; kc += 32) {
    #pragma unroll
    for (int t2 = 0; t2 < 2; ++t2) {
      int c0 = kc + (t2 << 4);
      short8 kf0 = *(const short8*)(Kb + (size_t)(c0 + lr) * 64 + 8 * lg);
      short8 kf1 = *(const short8*)(Kb + (size_t)(c0 + lr) * 64 + 32 + 8 * lg);
      f32x4 s = (f32x4){0.f, 0.f, 0.f, 0.f};
      s = __builtin_amdgcn_mfma_f32_16x16x32_bf16(kf0, qf0, s, 0, 0, 0);
      s = __builtin_amdgcn_mfma_f32_16x16x32_bf16(kf1, qf1, s, 0, 0, 0);
      float4 m4 = *(const float4*)(Mrow + c0 + (lg << 2));
      float p0 = __expf(fmaf(s[0], 0.125f, fmaf(m4.x, gamma, -shift))) * inv;
      float p1 = __expf(fmaf(s[1], 0.125f, fmaf(m4.y, gamma, -shift))) * inv;
      float p2 = __expf(fmaf(s[2], 0.125f, fmaf(m4.z, gamma, -shift))) * inv;
      float p3 = __expf(fmaf(s[3], 0.125f, fmaf(m4.w, gamma, -shift))) * inv;
      float4 pv4; pv4.x = p0; pv4.y = p1; pv4.z = p2; pv4.w = p3;
      *(float4*)(Arow + c0 + (lg << 2)) = pv4;
      unsigned lo = (unsigned)(unsigned short)f2bf(p0) | ((unsigned)(unsigned short)f2bf(p1) << 16);
      unsigned hi = (unsigned)(unsigned short)f2bf(p2) | ((unsigned)(unsigned short)f2bf(p3) << 16);
      uint2 pw; pw.x = lo; pw.y = hi;
      *(uint2*)(&P_lds[wave][lr][(t2 << 4) + (lg << 2)]) = pw;
    }
    asm volatile("s_waitcnt lgkmcnt(0)" ::: "memory");
    short8 pf = *(const short8*)(&P_lds[wave][lr][lg << 3]);
    #pragma unroll
    for (int j = 0; j < 4; j++) {
      short8 vf = *(const short8*)(Vb + (size_t)((j << 4) + lr) * 2048 + kc + (lg << 3));
      oacc[j] = __builtin_amdgcn_mfma_f32_16x16x32_bf16(pf, vf, oacc[j], 0, 0, 0);
    }
    asm volatile("s_waitcnt lgkmcnt(0)" ::: "memory");
  }

  #pragma unroll
  for (int j = 0; j < 4; j++)
    #pragma unroll
    for (int r = 0; r < 4; r++) {
      int qq = qb + (lg << 2) + r;
      out[((size_t)(bb * 2048) + qq) * 512 + (h << 6) + (j << 4) + lr] = oacc[j][r];
    }
}

extern "C" void kernel_launch(void* const* d_in, const int* in_sizes, int n_in,
                              void* d_out, int out_size, void* d_ws, size_t ws_size,
                              hipStream_t stream) {
  const float* q    = (const float*)d_in[0];
  const float* k    = (const float*)d_in[1];
  const float* v    = (const float*)d_in[2];
  const float* mask = (const float*)d_in[3];
  const float* Wq   = (const float*)d_in[4];
  const float* Wk   = (const float*)d_in[5];
  const float* Wv   = (const float*)d_in[6];
  const float* gma  = (const float*)d_in[7];
  float* out = (float*)d_out;
  float* attn_out = out + (size_t)4 * 2048 * 512;

  short* wt = (short*)d_ws;                              // 1.5 MB
  short* qh = (short*)((char*)d_ws + (2u << 20));        // 8 MB
  short* kh = qh + (size_t)4 * 8 * 2048 * 64;            // 8 MB
  short* vt = kh + (size_t)4 * 8 * 2048 * 64;            // 8 MB
  short* xb = vt + (size_t)4 * 8 * 2048 * 64;            // 24 MB (optional)
  bool big_ws = ws_size >= (size_t)(50u << 20);

  hipLaunchKernelGGL(prep_wt_k, dim3(3072), dim3(256), 0, stream, Wq, Wk, Wv, wt);
  if (big_ws) {
    hipLaunchKernelGGL(xcvt_k, dim3(6144), dim3(256), 0, stream, q, k, v, xb);
    hipLaunchKernelGGL(proj_k<1>, dim3(3072), dim3(64), 0, stream, q, k, v, xb, wt, qh, kh, vt);
  } else {
    hipLaunchKernelGGL(proj_k<0>, dim3(3072), dim3(64), 0, stream, q, k, v, xb, wt, qh, kh, vt);
  }
  hipLaunchKernelGGL(attn_k, dim3(2048), dim3(128), 0, stream, qh, kh, vt, mask, gma,
                     out, attn_out);
}

// Round 3
// 572.681 us; speedup vs baseline: 1.0573x; 1.0248x over previous
//
#include <hip/hip_runtime.h>

// B=4, S=2048, D=512, H=8, DK=DV=64
typedef __attribute__((ext_vector_type(8))) short short8;
typedef __attribute__((ext_vector_type(4))) float f32x4;

__device__ __forceinline__ short f2bf(float f) {
  union { float f; unsigned u; } x; x.f = f;
  return (short)((x.u + 0x7FFFu + ((x.u >> 16) & 1u)) >> 16);
}

// Wt[m][n][k] = W_m[k][n], bf16  (3 x 512 x 512)
__global__ __launch_bounds__(256) void prep_wt_k(const float* __restrict__ Wq,
    const float* __restrict__ Wk, const float* __restrict__ Wv,
    short* __restrict__ wt) {
  int idx = blockIdx.x * 256 + threadIdx.x;
  int m = idx >> 18;
  int r = idx & 0x3FFFF;
  int k = r >> 9, n = r & 511;
  const float* W = (m == 0) ? Wq : (m == 1) ? Wk : Wv;
  wt[(m << 18) + (n << 9) + k] = f2bf(W[(k << 9) + n]);
}

// convert q,k,v f32 -> bf16 [3][8192][512]
__global__ __launch_bounds__(256) void xcvt_k(const float* __restrict__ q,
    const float* __restrict__ k_, const float* __restrict__ v,
    short* __restrict__ xb) {
  int i = blockIdx.x * 256 + threadIdx.x;
  int m = i >> 19;
  int r = i & 0x7FFFF;
  const float* X = (m == 0) ? q : (m == 1) ? k_ : v;
  float4 f0 = ((const float4*)X)[2 * r];
  float4 f1 = ((const float4*)X)[2 * r + 1];
  short8 t;
  t[0] = f2bf(f0.x); t[1] = f2bf(f0.y); t[2] = f2bf(f0.z); t[3] = f2bf(f0.w);
  t[4] = f2bf(f1.x); t[5] = f2bf(f1.y); t[6] = f2bf(f1.z); t[7] = f2bf(f1.w);
  *(short8*)(xb + (size_t)i * 8) = t;
}

// X[8192][512] @ Wt[n][k] -> qh/kh [b][h][s][64] bf16, vt [b][h][dv][s] bf16
template<int BF>
__global__ __launch_bounds__(64) void proj_k(const float* __restrict__ q,
    const float* __restrict__ k_, const float* __restrict__ v,
    const short* __restrict__ xb, const short* __restrict__ wt,
    short* __restrict__ qh, short* __restrict__ kh, short* __restrict__ vt) {
  int bid = blockIdx.x;
  int mat = bid >> 10;
  int t = bid & 1023;
  int tm = t >> 3, tn = t & 7;
  const float* X = (mat == 0) ? q : (mat == 1) ? k_ : v;
  const short* Xb = xb + ((size_t)mat << 22);
  const short* W = wt + ((size_t)mat << 18);
  int lane = threadIdx.x;
  int lr = lane & 15, lg = lane >> 4;
  int m0 = tm << 6, n0 = tn << 6;
  f32x4 acc[4][4];
  #pragma unroll
  for (int i = 0; i < 4; i++)
    #pragma unroll
    for (int j = 0; j < 4; j++) acc[i][j] = (f32x4){0.f, 0.f, 0.f, 0.f};
  for (int k0 = 0; k0 < 512; k0 += 32) {
    short8 a[4], bfr[4];
    #pragma unroll
    for (int i = 0; i < 4; i++) {
      if (BF) {
        a[i] = *(const short8*)(Xb + (size_t)(m0 + 16 * i + lr) * 512 + k0 + 8 * lg);
      } else {
        const float* p = X + (size_t)(m0 + 16 * i + lr) * 512 + k0 + 8 * lg;
        float4 f0 = *(const float4*)p;
        float4 f1 = *(const float4*)(p + 4);
        short8 tt;
        tt[0] = f2bf(f0.x); tt[1] = f2bf(f0.y); tt[2] = f2bf(f0.z); tt[3] = f2bf(f0.w);
        tt[4] = f2bf(f1.x); tt[5] = f2bf(f1.y); tt[6] = f2bf(f1.z); tt[7] = f2bf(f1.w);
        a[i] = tt;
      }
    }
    #pragma unroll
    for (int j = 0; j < 4; j++)
      bfr[j] = *(const short8*)(W + (size_t)(n0 + 16 * j + lr) * 512 + k0 + 8 * lg);
    #pragma unroll
    for (int i = 0; i < 4; i++)
      #pragma unroll
      for (int j = 0; j < 4; j++)
        acc[i][j] = __builtin_amdgcn_mfma_f32_16x16x32_bf16(a[i], bfr[j], acc[i][j], 0, 0, 0);
  }
  #pragma unroll
  for (int i = 0; i < 4; i++)
    #pragma unroll
    for (int j = 0; j < 4; j++)
      #pragma unroll
      for (int r = 0; r < 4; r++) {
        int row = m0 + 16 * i + lg * 4 + r;
        int col = n0 + 16 * j + lr;
        int bb = row >> 11, s = row & 2047;
        int h = col >> 6, d = col & 63;
        short val = f2bf(acc[i][j][r]);
        if (mat == 0)      qh[((size_t)((bb * 8 + h) * 2048 + s) << 6) + d] = val;
        else if (mat == 1) kh[((size_t)((bb * 8 + h) * 2048 + s) << 6) + d] = val;
        else               vt[((size_t)((bb * 8 + h) * 64 + d) << 11) + s] = val;
      }
}

// swapped-operand attention; P exchanged via shfl (no LDS, no barriers)
__global__ __launch_bounds__(128) void attn_k(const short* __restrict__ qh,
    const short* __restrict__ kh, const short* __restrict__ vt,
    const float* __restrict__ mask, const float* __restrict__ gamma_p,
    float* __restrict__ out, float* __restrict__ attn_out) {
  int bid = blockIdx.x;
  int bh = bid >> 6;             // b*8+h
  int qblk = bid & 63;           // 32 q rows per block
  int bb = bh >> 3, h = bh & 7;
  int wave = threadIdx.x >> 6;
  int lane = threadIdx.x & 63;
  int lr = lane & 15, lg = lane >> 4;
  int qb = (qblk << 5) + (wave << 4);
  int qg = qb + lr;
  const short* Kb = kh + (size_t)bh * (2048 * 64);
  const short* Qb = qh + (size_t)bh * (2048 * 64);
  const short* Vb = vt + (size_t)bh * (64 * 2048);
  const float* Mrow = mask + (size_t)bb * (2048 * 2048) + (size_t)qg * 2048;
  float* Arow = attn_out + ((size_t)bh * 2048 + qg) * 2048;
  const float LOG2E = 1.4426950408889634f;
  float gamma = gamma_p[0];
  float shift = fmaxf(gamma, 0.f) + 16.0f;
  float cs = 0.125f * LOG2E;          // score scale in log2 domain
  float gl2 = gamma * LOG2E;
  float sh2 = shift * LOG2E;

  short8 qf0 = *(const short8*)(Qb + (size_t)qg * 64 + 8 * lg);
  short8 qf1 = *(const short8*)(Qb + (size_t)qg * 64 + 32 + 8 * lg);

  // ---- pass A: row sums ----
  float lsum = 0.f;
  for (int kc = 0; kc < 2048; kc += 32) {
    short8 kf00 = *(const short8*)(Kb + (size_t)(kc + lr) * 64 + 8 * lg);
    short8 kf01 = *(const short8*)(Kb + (size_t)(kc + lr) * 64 + 32 + 8 * lg);
    short8 kf10 = *(const short8*)(Kb + (size_t)(kc + 16 + lr) * 64 + 8 * lg);
    short8 kf11 = *(const short8*)(Kb + (size_t)(kc + 16 + lr) * 64 + 32 + 8 * lg);
    float4 m40 = *(const float4*)(Mrow + kc + (lg << 2));
    float4 m41 = *(const float4*)(Mrow + kc + 16 + (lg << 2));
    f32x4 s0 = (f32x4){0.f, 0.f, 0.f, 0.f};
    s0 = __builtin_amdgcn_mfma_f32_16x16x32_bf16(kf00, qf0, s0, 0, 0, 0);
    s0 = __builtin_amdgcn_mfma_f32_16x16x32_bf16(kf01, qf1, s0, 0, 0, 0);
    f32x4 s1 = (f32x4){0.f, 0.f, 0.f, 0.f};
    s1 = __builtin_amdgcn_mfma_f32_16x16x32_bf16(kf10, qf0, s1, 0, 0, 0);
    s1 = __builtin_amdgcn_mfma_f32_16x16x32_bf16(kf11, qf1, s1, 0, 0, 0);
    lsum += __builtin_amdgcn_exp2f(fmaf(s0[0], cs, fmaf(m40.x, gl2, -sh2)));
    lsum += __builtin_amdgcn_exp2f(fmaf(s0[1], cs, fmaf(m40.y, gl2, -sh2)));
    lsum += __builtin_amdgcn_exp2f(fmaf(s0[2], cs, fmaf(m40.z, gl2, -sh2)));
    lsum += __builtin_amdgcn_exp2f(fmaf(s0[3], cs, fmaf(m40.w, gl2, -sh2)));
    lsum += __builtin_amdgcn_exp2f(fmaf(s1[0], cs, fmaf(m41.x, gl2, -sh2)));
    lsum += __builtin_amdgcn_exp2f(fmaf(s1[1], cs, fmaf(m41.y, gl2, -sh2)));
    lsum += __builtin_amdgcn_exp2f(fmaf(s1[2], cs, fmaf(m41.z, gl2, -sh2)));
    lsum += __builtin_amdgcn_exp2f(fmaf(s1[3], cs, fmaf(m41.w, gl2, -sh2)));
  }
  lsum += __shfl_xor(lsum, 16);
  lsum += __shfl_xor(lsum, 32);
  float inv = 1.0f / lsum;

  // ---- pass B: recompute, write attn, PV via shfl-built fragments ----
  f32x4 oacc[4];
  #pragma unroll
  for (int j = 0; j < 4; j++) oacc[j] = (f32x4){0.f, 0.f, 0.f, 0.f};

  int sA = lr + 16 * ((2 * lg) & 3);       // source lanes for A-frag build
  int sB = lr + 16 * ((2 * lg + 1) & 3);
  bool loA = (lg < 2);

  for (int kc = 0; kc < 2048; kc += 32) {
    short8 kf00 = *(const short8*)(Kb + (size_t)(kc + lr) * 64 + 8 * lg);
    short8 kf01 = *(const short8*)(Kb + (size_t)(kc + lr) * 64 + 32 + 8 * lg);
    short8 kf10 = *(const short8*)(Kb + (size_t)(kc + 16 + lr) * 64 + 8 * lg);
    short8 kf11 = *(const short8*)(Kb + (size_t)(kc + 16 + lr) * 64 + 32 + 8 * lg);
    short8 vf0 = *(const short8*)(Vb + (size_t)(0  + lr) * 2048 + kc + (lg << 3));
    short8 vf1 = *(const short8*)(Vb + (size_t)(16 + lr) * 2048 + kc + (lg << 3));
    short8 vf2 = *(const short8*)(Vb + (size_t)(32 + lr) * 2048 + kc + (lg << 3));
    short8 vf3 = *(const short8*)(Vb + (size_t)(48 + lr) * 2048 + kc + (lg << 3));
    float4 m40 = *(const float4*)(Mrow + kc + (lg << 2));
    float4 m41 = *(const float4*)(Mrow + kc + 16 + (lg << 2));

    f32x4 s0 = (f32x4){0.f, 0.f, 0.f, 0.f};
    s0 = __builtin_amdgcn_mfma_f32_16x16x32_bf16(kf00, qf0, s0, 0, 0, 0);
    s0 = __builtin_amdgcn_mfma_f32_16x16x32_bf16(kf01, qf1, s0, 0, 0, 0);
    f32x4 s1 = (f32x4){0.f, 0.f, 0.f, 0.f};
    s1 = __builtin_amdgcn_mfma_f32_16x16x32_bf16(kf10, qf0, s1, 0, 0, 0);
    s1 = __builtin_amdgcn_mfma_f32_16x16x32_bf16(kf11, qf1, s1, 0, 0, 0);

    float p00 = __builtin_amdgcn_exp2f(fmaf(s0[0], cs, fmaf(m40.x, gl2, -sh2))) * inv;
    float p01 = __builtin_amdgcn_exp2f(fmaf(s0[1], cs, fmaf(m40.y, gl2, -sh2))) * inv;
    float p02 = __builtin_amdgcn_exp2f(fmaf(s0[2], cs, fmaf(m40.z, gl2, -sh2))) * inv;
    float p03 = __builtin_amdgcn_exp2f(fmaf(s0[3], cs, fmaf(m40.w, gl2, -sh2))) * inv;
    float p10 = __builtin_amdgcn_exp2f(fmaf(s1[0], cs, fmaf(m41.x, gl2, -sh2))) * inv;
    float p11 = __builtin_amdgcn_exp2f(fmaf(s1[1], cs, fmaf(m41.y, gl2, -sh2))) * inv;
    float p12 = __builtin_amdgcn_exp2f(fmaf(s1[2], cs, fmaf(m41.z, gl2, -sh2))) * inv;
    float p13 = __builtin_amdgcn_exp2f(fmaf(s1[3], cs, fmaf(m41.w, gl2, -sh2))) * inv;

    float4 a0; a0.x = p00; a0.y = p01; a0.z = p02; a0.w = p03;
    float4 a1; a1.x = p10; a1.y = p11; a1.z = p12; a1.w = p13;
    *(float4*)(Arow + kc + (lg << 2)) = a0;
    *(float4*)(Arow + kc + 16 + (lg << 2)) = a1;

    // pack unnormalized-scale bf16 P words: w0,w1 (k=4lg..4lg+3), w2,w3 (k=16+4lg..)
    unsigned w0 = (unsigned)(unsigned short)f2bf(p00) | ((unsigned)(unsigned short)f2bf(p01) << 16);
    unsigned w1 = (unsigned)(unsigned short)f2bf(p02) | ((unsigned)(unsigned short)f2bf(p03) << 16);
    unsigned w2 = (unsigned)(unsigned short)f2bf(p10) | ((unsigned)(unsigned short)f2bf(p11) << 16);
    unsigned w3 = (unsigned)(unsigned short)f2bf(p12) | ((unsigned)(unsigned short)f2bf(p13) << 16);

    unsigned x0 = __shfl((int)w0, sA), x1 = __shfl((int)w1, sA);
    unsigned x2 = __shfl((int)w2, sA), x3 = __shfl((int)w3, sA);
    unsigned y0 = __shfl((int)w0, sB), y1 = __shfl((int)w1, sB);
    unsigned y2 = __shfl((int)w2, sB), y3 = __shfl((int)w3, sB);

    union { unsigned u[4]; short8 s8; } pu;
    pu.u[0] = loA ? x0 : x2;
    pu.u[1] = loA ? x1 : x3;
    pu.u[2] = loA ? y0 : y2;
    pu.u[3] = loA ? y1 : y3;

    oacc[0] = __builtin_amdgcn_mfma_f32_16x16x32_bf16(pu.s8, vf0, oacc[0], 0, 0, 0);
    oacc[1] = __builtin_amdgcn_mfma_f32_16x16x32_bf16(pu.s8, vf1, oacc[1], 0, 0, 0);
    oacc[2] = __builtin_amdgcn_mfma_f32_16x16x32_bf16(pu.s8, vf2, oacc[2], 0, 0, 0);
    oacc[3] = __builtin_amdgcn_mfma_f32_16x16x32_bf16(pu.s8, vf3, oacc[3], 0, 0, 0);
  }

  #pragma unroll
  for (int j = 0; j < 4; j++)
    #pragma unroll
    for (int r = 0; r < 4; r++) {
      int qq = qb + (lg << 2) + r;
      out[((size_t)(bb * 2048) + qq) * 512 + (h << 6) + (j << 4) + lr] = oacc[j][r];
    }
}

extern "C" void kernel_launch(void* const* d_in, const int* in_sizes, int n_in,
                              void* d_out, int out_size, void* d_ws, size_t ws_size,
                              hipStream_t stream) {
  const float* q    = (const float*)d_in[0];
  const float* k    = (const float*)d_in[1];
  const float* v    = (const float*)d_in[2];
  const float* mask = (const float*)d_in[3];
  const float* Wq   = (const float*)d_in[4];
  const float* Wk   = (const float*)d_in[5];
  const float* Wv   = (const float*)d_in[6];
  const float* gma  = (const float*)d_in[7];
  float* out = (float*)d_out;
  float* attn_out = out + (size_t)4 * 2048 * 512;

  short* wt = (short*)d_ws;                              // 1.5 MB
  short* qh = (short*)((char*)d_ws + (2u << 20));        // 8 MB
  short* kh = qh + (size_t)4 * 8 * 2048 * 64;            // 8 MB
  short* vt = kh + (size_t)4 * 8 * 2048 * 64;            // 8 MB
  short* xb = vt + (size_t)4 * 8 * 2048 * 64;            // 24 MB (optional)
  bool big_ws = ws_size >= (size_t)(50u << 20);

  hipLaunchKernelGGL(prep_wt_k, dim3(3072), dim3(256), 0, stream, Wq, Wk, Wv, wt);
  if (big_ws) {
    hipLaunchKernelGGL(xcvt_k, dim3(6144), dim3(256), 0, stream, q, k, v, xb);
    hipLaunchKernelGGL(proj_k<1>, dim3(3072), dim3(64), 0, stream, q, k, v, xb, wt, qh, kh, vt);
  } else {
    hipLaunchKernelGGL(proj_k<0>, dim3(3072), dim3(64), 0, stream, q, k, v, xb, wt, qh, kh, vt);
  }
  hipLaunchKernelGGL(attn_k, dim3(2048), dim3(128), 0, stream, qh, kh, vt, mask, gma,
                     out, attn_out);
}